// Round 4
// baseline (351.935 us; speedup 1.0000x reference)
//
#include <hip/hip_runtime.h>

#define NW    16
#define NEUR  128
#define NPTS  65536
#define SIGMA 0.02f
#define U_MEAN 0.0f
#define U_SD   1.0f
#define DELTA 0.19f          // cull radius: err <= 2.1*11.4*exp(-(DELTA+0.0625)/SIGMA) ~ 8e-5

#define TILE   128          // points per block
#define NTHR   512          // 8 waves
#define HPAD   136          // 272B rows: 16B-aligned (132 caused misaligned-b128 HW replay, R2)
#define WMAT_HALVES (NEUR*HPAD)           // 17408 halves = 34816 B per weight matrix (2176 float4)
#define WT_TOTAL (2*NW*WMAT_HALVES)       // 557056 halves = 1,114,112 B
#define WT_BYTES (WT_TOTAL*2)
#define CNT_OFF  WT_BYTES                 // 16 ints
#define IDX_OFF  (WT_BYTES + 128)         // u16 lists
#define CHUNKS 240
#define CAP    (CHUNKS*TILE)              // 30720 slots/window (interior windows need ~29000)

typedef _Float16 half8 __attribute__((ext_vector_type(8)));
typedef float    f32x4 __attribute__((ext_vector_type(4)));

__device__ __forceinline__ float tanh_fast(float x) {
    float e = __expf(2.0f * x);
    return 1.0f - 2.0f * __builtin_amdgcn_rcpf(1.0f + e);
}

// W_hid fp32 [l][w][d][e] -> wt fp16 [(l*NW+w)][e][HPAD] (k=d contiguous, padded)
__global__ void prep_kernel(const float* __restrict__ W_hid, _Float16* __restrict__ wt) {
    int idx  = blockIdx.x * 256 + threadIdx.x;     // 2176*256 = 557056
    int d    = idx % HPAD;
    int rest = idx / HPAD;
    int e    = rest & (NEUR - 1);
    int lw   = rest >> 7;
    _Float16 v = (_Float16)0.0f;
    if (d < NEUR) v = (_Float16)W_hid[(lw * NEUR + d) * NEUR + e];
    wt[idx] = v;
}

// per-point window membership -> 16 compacted u16 index lists (per-wave aggregated atomics)
__global__ void bucket_kernel(const float* __restrict__ x, const float* __restrict__ mids,
                              int* __restrict__ cnt, unsigned short* __restrict__ idx) {
    int i    = blockIdx.x * 256 + threadIdx.x;
    int lane = threadIdx.x & 63;
    float xv = x[i];
#pragma unroll
    for (int w = 0; w < NW; ++w) {
        bool need = (xv >= mids[w] - DELTA) && (xv <= mids[w + 1] + DELTA);
        unsigned long long mask = __ballot(need);
        if (mask) {
            int leader = (int)__builtin_ctzll(mask);
            int total  = (int)__popcll(mask);
            int rank   = (int)__popcll(mask & ((1ull << lane) - 1ull));
            int base = 0;
            if (lane == leader) base = atomicAdd(&cnt[w], total);
            base = __shfl(base, leader);
            if (need) {
                int slot = base + rank;
                if (slot < CAP) idx[w * CAP + slot] = (unsigned short)i;
            }
        }
    }
}

// acc[c] = 16x16 tile c of Hlds[128rows x 128k] @ Wlds[128n x 128k]^T
__device__ __forceinline__ void gemm_tile(const _Float16* Hbase, const _Float16* Wbase,
                                          int row0, int m, int q, f32x4 acc[8]) {
    const f32x4 z = {0.f, 0.f, 0.f, 0.f};
#pragma unroll
    for (int c = 0; c < 8; ++c) acc[c] = z;
#pragma unroll
    for (int s = 0; s < 4; ++s) {
        half8 a = *(const half8*)(Hbase + (row0 + m) * HPAD + s * 32 + q * 8);
#pragma unroll
        for (int c = 0; c < 8; ++c) {
            half8 b = *(const half8*)(Wbase + (c * 16 + m) * HPAD + s * 32 + q * 8);
            acc[c] = __builtin_amdgcn_mfma_f32_16x16x32_f16(a, b, acc[c], 0, 0, 0);
        }
    }
}

__device__ __forceinline__ void act_store(_Float16* Hbase, const float* __restrict__ bias,
                                          int row0, int m, int q, const f32x4 acc[8]) {
#pragma unroll
    for (int c = 0; c < 8; ++c) {
        float b = bias[c * 16 + m];
#pragma unroll
        for (int r = 0; r < 4; ++r) {
            // C/D layout: col = lane&15 (=m), row = q*4 + r
            Hbase[(row0 + q * 4 + r) * HPAD + c * 16 + m] = (_Float16)tanh_fast(acc[c][r] + b);
        }
    }
}

__device__ __forceinline__ void stage_w(const float4* __restrict__ g, float4* l4, int t) {
    float4 r0 = g[t], r1 = g[t + 512], r2 = g[t + 1024], r3 = g[t + 1536];
    float4 r4;
    if (t < 128) r4 = g[t + 2048];
    l4[t] = r0; l4[t + 512] = r1; l4[t + 1024] = r2; l4[t + 1536] = r3;
    if (t < 128) l4[t + 2048] = r4;
}

__global__ __launch_bounds__(NTHR, 4) void fbpinn_main(
    const float* __restrict__ x,     const float* __restrict__ means,
    const float* __restrict__ stds,  const float* __restrict__ mids,
    const float* __restrict__ W_in,  const float* __restrict__ b_in,
    const float* __restrict__ b_hid, const float* __restrict__ W_out,
    const float* __restrict__ b_out, const _Float16* __restrict__ wt,
    const int* __restrict__ cnt,     const unsigned short* __restrict__ idx,
    float* __restrict__ out)
{
    const int w = blockIdx.y;
    int cntw = cnt[w]; if (cntw > CAP) cntw = CAP;
    const int base = blockIdx.x * TILE;
    if (base >= cntw) return;
    const int nvalid = min(TILE, cntw - base);

    __shared__ __align__(16) _Float16 Wlds[WMAT_HALVES];   // 34816 B
    __shared__ __align__(16) _Float16 Hlds[TILE * HPAD];   // 34816 B
    __shared__ float xs[TILE];
    __shared__ float wouts[NEUR];
    __shared__ unsigned short gis[TILE];

    const int t    = threadIdx.x;
    const int lane = t & 63;
    const int wave = t >> 6;
    const int m    = lane & 15;
    const int q    = lane >> 4;
    const int row0 = wave * 16;
    const int p    = t & 127;
    const int qq   = t >> 7;
    const int rsel = m & 3;

    // gather this chunk's points; clamp tail lanes to last valid (results discarded)
    if (t < TILE) {
        int s = min(t, nvalid - 1);
        unsigned short gi = idx[w * CAP + base + s];
        gis[t] = gi;
        xs[t]  = x[gi];
    }
    stage_w((const float4*)(wt + (size_t)(0 * NW + w) * WMAT_HALVES), (float4*)Wlds, t);
    if (t < NEUR) wouts[t] = W_out[w * NEUR + t];
    __syncthreads();   // xs/gis visible

    // layer 0 (1->128) fp32, b128 stores
    const float xn = (xs[p] - means[w]) * __builtin_amdgcn_rcpf(stds[w]);
    const float* win = W_in + w * NEUR;
    const float* bin = b_in + w * NEUR;
#pragma unroll
    for (int i8 = 0; i8 < 4; ++i8) {
        const int n0 = qq * 32 + i8 * 8;
        float4 wv0 = *(const float4*)&win[n0];
        float4 wv1 = *(const float4*)&win[n0 + 4];
        float4 bv0 = *(const float4*)&bin[n0];
        float4 bv1 = *(const float4*)&bin[n0 + 4];
        half8 hv;
        hv[0] = (_Float16)tanh_fast(fmaf(xn, wv0.x, bv0.x));
        hv[1] = (_Float16)tanh_fast(fmaf(xn, wv0.y, bv0.y));
        hv[2] = (_Float16)tanh_fast(fmaf(xn, wv0.z, bv0.z));
        hv[3] = (_Float16)tanh_fast(fmaf(xn, wv0.w, bv0.w));
        hv[4] = (_Float16)tanh_fast(fmaf(xn, wv1.x, bv1.x));
        hv[5] = (_Float16)tanh_fast(fmaf(xn, wv1.y, bv1.y));
        hv[6] = (_Float16)tanh_fast(fmaf(xn, wv1.z, bv1.z));
        hv[7] = (_Float16)tanh_fast(fmaf(xn, wv1.w, bv1.w));
        *(half8*)&Hlds[p * HPAD + n0] = hv;
    }
    __syncthreads();   // h1, W0, wouts visible

    f32x4 acc[8];
    gemm_tile(Hlds, Wlds, row0, m, q, acc);          // z2 = h1 @ W0^T-frag
    __syncthreads();

    stage_w((const float4*)(wt + (size_t)(1 * NW + w) * WMAT_HALVES), (float4*)Wlds, t);
    act_store(Hlds, b_hid + (0 * NW + w) * NEUR, row0, m, q, acc);   // h2
    __syncthreads();

    gemm_tile(Hlds, Wlds, row0, m, q, acc);          // z3 = h2 @ W1^T-frag

    // register epilogue: h3 = tanh(z3+b); out = h3 . W_out ; reduce over 16 m-lanes
    const float* bh1 = b_hid + (1 * NW + w) * NEUR;
    float t0 = 0.f, t1 = 0.f, t2 = 0.f, t3 = 0.f;
#pragma unroll
    for (int c = 0; c < 8; ++c) {
        float b  = bh1[c * 16 + m];
        float wo = wouts[c * 16 + m];
        t0 = fmaf(tanh_fast(acc[c][0] + b), wo, t0);
        t1 = fmaf(tanh_fast(acc[c][1] + b), wo, t1);
        t2 = fmaf(tanh_fast(acc[c][2] + b), wo, t2);
        t3 = fmaf(tanh_fast(acc[c][3] + b), wo, t3);
    }
    t0 += __shfl_xor(t0, 1); t1 += __shfl_xor(t1, 1);
    t2 += __shfl_xor(t2, 1); t3 += __shfl_xor(t3, 1);
    t0 += __shfl_xor(t0, 2); t1 += __shfl_xor(t1, 2);
    t2 += __shfl_xor(t2, 2); t3 += __shfl_xor(t3, 2);
    float v = (rsel == 0) ? t0 : (rsel == 1) ? t1 : (rsel == 2) ? t2 : t3;
    v += __shfl_xor(v, 4);
    v += __shfl_xor(v, 8);

    const int slot = row0 + q * 4 + rsel;
    if (m < 4 && slot < nvalid) {
        float u   = (v + b_out[w]) * U_SD + U_MEAN;
        float xv  = xs[slot];
        float xl  = (xv - mids[w])     * (1.0f / SIGMA);
        float xr  = (xv - mids[w + 1]) * (1.0f / SIGMA);
        float wf  = __builtin_amdgcn_rcpf(1.0f + __expf(xl)) *
                    __builtin_amdgcn_rcpf(1.0f + __expf(-xr));
        atomicAdd(&out[gis[slot]], wf * u);
    }
}

extern "C" void kernel_launch(void* const* d_in, const int* in_sizes, int n_in,
                              void* d_out, int out_size, void* d_ws, size_t ws_size,
                              hipStream_t stream) {
    const float* x     = (const float*)d_in[0];
    const float* means = (const float*)d_in[1];
    const float* stds  = (const float*)d_in[2];
    const float* mids  = (const float*)d_in[3];
    const float* W_in  = (const float*)d_in[4];
    const float* b_in  = (const float*)d_in[5];
    const float* W_hid = (const float*)d_in[6];
    const float* b_hid = (const float*)d_in[7];
    const float* W_out = (const float*)d_in[8];
    const float* b_out = (const float*)d_in[9];
    float* out = (float*)d_out;

    _Float16*       wt   = (_Float16*)d_ws;                       // 1,114,112 B
    int*            cnt  = (int*)((char*)d_ws + CNT_OFF);         // 64 B
    unsigned short* idx  = (unsigned short*)((char*)d_ws + IDX_OFF); // 983,040 B (total ~2.1 MB)

    hipMemsetAsync(out, 0, NPTS * sizeof(float), stream);
    hipMemsetAsync(cnt, 0, 64, stream);
    prep_kernel<<<WT_TOTAL / 256, 256, 0, stream>>>(W_hid, wt);
    bucket_kernel<<<NPTS / 256, 256, 0, stream>>>(x, mids, cnt, idx);
    fbpinn_main<<<dim3(CHUNKS, NW), NTHR, 0, stream>>>(
        x, means, stds, mids, W_in, b_in, b_hid, W_out, b_out, wt, cnt, idx, out);
}

// Round 5
// 213.864 us; speedup vs baseline: 1.6456x; 1.6456x over previous
//
#include <hip/hip_runtime.h>

#define NW    16
#define NEUR  128
#define NPTS  65536
#define SIGMA 0.02f
#define U_MEAN 0.0f
#define U_SD   1.0f
#define DELTA 0.19f          // cull radius: err <= 2.1*11.4*exp(-(DELTA+0.0625)/SIGMA) ~ 8e-5

#define TILE   128          // points per block
#define NTHR   512          // 8 waves
#define HPAD   136          // 272B rows: 16B-aligned (132 caused misaligned-b128 HW replay, R2)
#define WMAT_HALVES (NEUR*HPAD)           // 17408 halves = 34816 B per weight matrix (2176 float4)
#define WT_TOTAL (2*NW*WMAT_HALVES)       // 557056 halves = 1,114,112 B
#define WT_BYTES (WT_TOTAL*2)
#define CNT_OFF  WT_BYTES                 // 16 ints
#define IDX_OFF  (WT_BYTES + 128)         // u16 lists
#define CHUNKS 240
#define CAP    (CHUNKS*TILE)              // 30720 slots/window (interior windows need ~29000)

typedef _Float16 half8 __attribute__((ext_vector_type(8)));
typedef float    f32x4 __attribute__((ext_vector_type(4)));

__device__ __forceinline__ float tanh_fast(float x) {
    float e = __expf(2.0f * x);
    return 1.0f - 2.0f * __builtin_amdgcn_rcpf(1.0f + e);
}

// W_hid fp32 [l][w][d][e] -> wt fp16 [(l*NW+w)][e][HPAD] (k=d contiguous, padded)
__global__ void prep_kernel(const float* __restrict__ W_hid, _Float16* __restrict__ wt) {
    int idx  = blockIdx.x * 256 + threadIdx.x;     // 2176*256 = 557056
    int d    = idx % HPAD;
    int rest = idx / HPAD;
    int e    = rest & (NEUR - 1);
    int lw   = rest >> 7;
    _Float16 v = (_Float16)0.0f;
    if (d < NEUR) v = (_Float16)W_hid[(lw * NEUR + d) * NEUR + e];
    wt[idx] = v;
}

// block w compacts indices of points needing window w. NO global atomics
// (R4's per-wave device atomicAdd on one cache line cost 188 us).
__global__ __launch_bounds__(512) void bucket16_kernel(
    const float* __restrict__ x, const float* __restrict__ mids,
    int* __restrict__ cnt, unsigned short* __restrict__ idx)
{
    const int w = blockIdx.x;              // 16 blocks
    __shared__ int lcnt;
    if (threadIdx.x == 0) lcnt = 0;
    __syncthreads();
    const float lo = mids[w] - DELTA;
    const float hi = mids[w + 1] + DELTA;
    const int lane = threadIdx.x & 63;
    unsigned short* lw_idx = idx + w * CAP;
#pragma unroll 4
    for (int it = 0; it < NPTS / 512; ++it) {
        int i = it * 512 + threadIdx.x;
        float xv = x[i];
        bool need = (xv >= lo) && (xv <= hi);
        unsigned long long mask = __ballot(need);
        if (mask) {
            int leader = (int)__builtin_ctzll(mask);
            int total  = (int)__popcll(mask);
            int rank   = (int)__popcll(mask & ((1ull << lane) - 1ull));
            int base = 0;
            if (lane == leader) base = atomicAdd(&lcnt, total);   // LDS atomic: cheap
            base = __shfl(base, leader);
            int slot = base + rank;
            if (need && slot < CAP) lw_idx[slot] = (unsigned short)i;
        }
    }
    __syncthreads();
    if (threadIdx.x == 0) cnt[w] = lcnt;
}

// acc[c] = 16x16 tile c of Hlds[128rows x 128k] @ Wlds[128n x 128k]^T
__device__ __forceinline__ void gemm_tile(const _Float16* Hbase, const _Float16* Wbase,
                                          int row0, int m, int q, f32x4 acc[8]) {
    const f32x4 z = {0.f, 0.f, 0.f, 0.f};
#pragma unroll
    for (int c = 0; c < 8; ++c) acc[c] = z;
#pragma unroll
    for (int s = 0; s < 4; ++s) {
        half8 a = *(const half8*)(Hbase + (row0 + m) * HPAD + s * 32 + q * 8);
#pragma unroll
        for (int c = 0; c < 8; ++c) {
            half8 b = *(const half8*)(Wbase + (c * 16 + m) * HPAD + s * 32 + q * 8);
            acc[c] = __builtin_amdgcn_mfma_f32_16x16x32_f16(a, b, acc[c], 0, 0, 0);
        }
    }
}

__device__ __forceinline__ void act_store(_Float16* Hbase, const float* __restrict__ bias,
                                          int row0, int m, int q, const f32x4 acc[8]) {
#pragma unroll
    for (int c = 0; c < 8; ++c) {
        float b = bias[c * 16 + m];
#pragma unroll
        for (int r = 0; r < 4; ++r) {
            // C/D layout: col = lane&15 (=m), row = q*4 + r
            Hbase[(row0 + q * 4 + r) * HPAD + c * 16 + m] = (_Float16)tanh_fast(acc[c][r] + b);
        }
    }
}

__device__ __forceinline__ void stage_w(const float4* __restrict__ g, float4* l4, int t) {
    float4 r0 = g[t], r1 = g[t + 512], r2 = g[t + 1024], r3 = g[t + 1536];
    float4 r4;
    if (t < 128) r4 = g[t + 2048];
    l4[t] = r0; l4[t + 512] = r1; l4[t + 1024] = r2; l4[t + 1536] = r3;
    if (t < 128) l4[t + 2048] = r4;
}

__global__ __launch_bounds__(NTHR, 4) void fbpinn_main(
    const float* __restrict__ x,     const float* __restrict__ means,
    const float* __restrict__ stds,  const float* __restrict__ mids,
    const float* __restrict__ W_in,  const float* __restrict__ b_in,
    const float* __restrict__ b_hid, const float* __restrict__ W_out,
    const float* __restrict__ b_out, const _Float16* __restrict__ wt,
    const int* __restrict__ cnt,     const unsigned short* __restrict__ idx,
    float* __restrict__ out)
{
    const int w = blockIdx.y;
    int cntw = cnt[w]; if (cntw > CAP) cntw = CAP;
    const int base = blockIdx.x * TILE;
    if (base >= cntw) return;
    const int nvalid = min(TILE, cntw - base);

    __shared__ __align__(16) _Float16 Wlds[WMAT_HALVES];   // 34816 B
    __shared__ __align__(16) _Float16 Hlds[TILE * HPAD];   // 34816 B
    __shared__ float xs[TILE];
    __shared__ float wouts[NEUR];
    __shared__ unsigned short gis[TILE];

    const int t    = threadIdx.x;
    const int lane = t & 63;
    const int wave = t >> 6;
    const int m    = lane & 15;
    const int q    = lane >> 4;
    const int row0 = wave * 16;
    const int p    = t & 127;
    const int qq   = t >> 7;
    const int rsel = m & 3;

    // gather this chunk's points; clamp tail lanes to last valid (results discarded)
    if (t < TILE) {
        int s = min(t, nvalid - 1);
        unsigned short gi = idx[w * CAP + base + s];
        gis[t] = gi;
        xs[t]  = x[gi];
    }
    stage_w((const float4*)(wt + (size_t)(0 * NW + w) * WMAT_HALVES), (float4*)Wlds, t);
    if (t < NEUR) wouts[t] = W_out[w * NEUR + t];
    __syncthreads();   // xs/gis visible

    // layer 0 (1->128) fp32, b128 stores
    const float xn = (xs[p] - means[w]) * __builtin_amdgcn_rcpf(stds[w]);
    const float* win = W_in + w * NEUR;
    const float* bin = b_in + w * NEUR;
#pragma unroll
    for (int i8 = 0; i8 < 4; ++i8) {
        const int n0 = qq * 32 + i8 * 8;
        float4 wv0 = *(const float4*)&win[n0];
        float4 wv1 = *(const float4*)&win[n0 + 4];
        float4 bv0 = *(const float4*)&bin[n0];
        float4 bv1 = *(const float4*)&bin[n0 + 4];
        half8 hv;
        hv[0] = (_Float16)tanh_fast(fmaf(xn, wv0.x, bv0.x));
        hv[1] = (_Float16)tanh_fast(fmaf(xn, wv0.y, bv0.y));
        hv[2] = (_Float16)tanh_fast(fmaf(xn, wv0.z, bv0.z));
        hv[3] = (_Float16)tanh_fast(fmaf(xn, wv0.w, bv0.w));
        hv[4] = (_Float16)tanh_fast(fmaf(xn, wv1.x, bv1.x));
        hv[5] = (_Float16)tanh_fast(fmaf(xn, wv1.y, bv1.y));
        hv[6] = (_Float16)tanh_fast(fmaf(xn, wv1.z, bv1.z));
        hv[7] = (_Float16)tanh_fast(fmaf(xn, wv1.w, bv1.w));
        *(half8*)&Hlds[p * HPAD + n0] = hv;
    }
    __syncthreads();   // h1, W0, wouts visible

    f32x4 acc[8];
    gemm_tile(Hlds, Wlds, row0, m, q, acc);          // z2 = h1 @ W0^T-frag
    __syncthreads();

    stage_w((const float4*)(wt + (size_t)(1 * NW + w) * WMAT_HALVES), (float4*)Wlds, t);
    act_store(Hlds, b_hid + (0 * NW + w) * NEUR, row0, m, q, acc);   // h2
    __syncthreads();

    gemm_tile(Hlds, Wlds, row0, m, q, acc);          // z3 = h2 @ W1^T-frag

    // register epilogue: h3 = tanh(z3+b); out = h3 . W_out ; reduce over 16 m-lanes
    const float* bh1 = b_hid + (1 * NW + w) * NEUR;
    float t0 = 0.f, t1 = 0.f, t2 = 0.f, t3 = 0.f;
#pragma unroll
    for (int c = 0; c < 8; ++c) {
        float b  = bh1[c * 16 + m];
        float wo = wouts[c * 16 + m];
        t0 = fmaf(tanh_fast(acc[c][0] + b), wo, t0);
        t1 = fmaf(tanh_fast(acc[c][1] + b), wo, t1);
        t2 = fmaf(tanh_fast(acc[c][2] + b), wo, t2);
        t3 = fmaf(tanh_fast(acc[c][3] + b), wo, t3);
    }
    t0 += __shfl_xor(t0, 1); t1 += __shfl_xor(t1, 1);
    t2 += __shfl_xor(t2, 1); t3 += __shfl_xor(t3, 1);
    t0 += __shfl_xor(t0, 2); t1 += __shfl_xor(t1, 2);
    t2 += __shfl_xor(t2, 2); t3 += __shfl_xor(t3, 2);
    float v = (rsel == 0) ? t0 : (rsel == 1) ? t1 : (rsel == 2) ? t2 : t3;
    v += __shfl_xor(v, 4);
    v += __shfl_xor(v, 8);

    const int slot = row0 + q * 4 + rsel;
    if (m < 4 && slot < nvalid) {
        float u   = (v + b_out[w]) * U_SD + U_MEAN;
        float xv  = xs[slot];
        float xl  = (xv - mids[w])     * (1.0f / SIGMA);
        float xr  = (xv - mids[w + 1]) * (1.0f / SIGMA);
        float wf  = __builtin_amdgcn_rcpf(1.0f + __expf(xl)) *
                    __builtin_amdgcn_rcpf(1.0f + __expf(-xr));
        atomicAdd(&out[gis[slot]], wf * u);
    }
}

extern "C" void kernel_launch(void* const* d_in, const int* in_sizes, int n_in,
                              void* d_out, int out_size, void* d_ws, size_t ws_size,
                              hipStream_t stream) {
    const float* x     = (const float*)d_in[0];
    const float* means = (const float*)d_in[1];
    const float* stds  = (const float*)d_in[2];
    const float* mids  = (const float*)d_in[3];
    const float* W_in  = (const float*)d_in[4];
    const float* b_in  = (const float*)d_in[5];
    const float* W_hid = (const float*)d_in[6];
    const float* b_hid = (const float*)d_in[7];
    const float* W_out = (const float*)d_in[8];
    const float* b_out = (const float*)d_in[9];
    float* out = (float*)d_out;

    _Float16*       wt   = (_Float16*)d_ws;                       // 1,114,112 B
    int*            cnt  = (int*)((char*)d_ws + CNT_OFF);         // 64 B (written directly, no memset)
    unsigned short* idx  = (unsigned short*)((char*)d_ws + IDX_OFF); // 983,040 B (total ~2.1 MB)

    hipMemsetAsync(out, 0, NPTS * sizeof(float), stream);
    prep_kernel<<<WT_TOTAL / 256, 256, 0, stream>>>(W_hid, wt);
    bucket16_kernel<<<NW, 512, 0, stream>>>(x, mids, cnt, idx);
    fbpinn_main<<<dim3(CHUNKS, NW), NTHR, 0, stream>>>(
        x, means, stds, mids, W_in, b_in, b_hid, W_out, b_out, wt, cnt, idx, out);
}

// Round 7
// 171.016 us; speedup vs baseline: 2.0579x; 1.2505x over previous
//
#include <hip/hip_runtime.h>

#define NW    16
#define NEUR  128
#define NPTS  65536
#define SIGMA 0.02f
#define U_MEAN 0.0f
#define U_SD   1.0f
#define DELTA 0.19f          // cull radius: err <= 2.1*11.4*exp(-(DELTA+0.0625)/SIGMA) ~ 8e-5

#define TILE   128          // points per block
#define NTHR   512          // 8 waves
#define HPAD   136          // 272B rows: 16B-aligned (132 caused misaligned-b128 HW replay, R2)
#define WMAT_HALVES (NEUR*HPAD)           // 17408 halves = 34816 B per matrix
#define WT_TOTAL (2*NW*WMAT_HALVES)       // 557056 halves = 1,114,112 B
#define WT_BYTES (WT_TOTAL*2)
#define CNT_OFF  WT_BYTES                 // 256 ints (cnt16[w*16+s])
#define IDX_OFF  (WT_BYTES + 1024)        // segmented u16 lists, 1 MB
#define NSEG   16
#define SEGPTS (NPTS/NSEG)                // 4096 points scanned per bucket block
#define CAPSEG 2048                       // max fill ~1910 (mean 1812 + 3sigma; edges ~1034)
#define CHUNKS 256                        // ceil(16*CAPSEG/TILE) upper bound

typedef _Float16 half8 __attribute__((ext_vector_type(8)));
typedef float    f32x4 __attribute__((ext_vector_type(4)));

__device__ __forceinline__ float tanh_fast(float x) {
    float e = __expf(2.0f * x);
    return 1.0f - 2.0f * __builtin_amdgcn_rcpf(1.0f + e);
}

// W_hid fp32 [l][w][d][e] -> wt fp16 [lw][e][HPAD] via LDS transpose.
// Coalesced global reads; output layout == LDS layout so store is a linear b128 copy.
__global__ __launch_bounds__(256) void prep2_kernel(const float* __restrict__ W_hid,
                                                    _Float16* __restrict__ wt) {
    __shared__ __align__(16) _Float16 tile[NEUR * HPAD];   // [e][136] halves, 34816 B
    const int lw = blockIdx.x;                             // 32 matrices
    const int t  = threadIdx.x;
    const float4* src = (const float4*)(W_hid + (size_t)lw * NEUR * NEUR);
#pragma unroll
    for (int it = 0; it < 16; ++it) {
        int f4 = it * 256 + t;            // float4 index over [d][e/4]
        int d  = f4 >> 5;
        int e0 = (f4 & 31) << 2;
        float4 v = src[f4];
        tile[(e0 + 0) * HPAD + d] = (_Float16)v.x;
        tile[(e0 + 1) * HPAD + d] = (_Float16)v.y;
        tile[(e0 + 2) * HPAD + d] = (_Float16)v.z;
        tile[(e0 + 3) * HPAD + d] = (_Float16)v.w;
    }
    if (t < NEUR) {                        // zero the k-pad halves d in [128,136)
        half8 z; for (int j = 0; j < 8; ++j) z[j] = (_Float16)0.0f;
        *(half8*)&tile[t * HPAD + NEUR] = z;
    }
    __syncthreads();
    _Float16* dst = wt + (size_t)lw * WMAT_HALVES;
#pragma unroll
    for (int it = 0; it < 9; ++it) {       // 2176 half8 chunks, linear copy
        int chunk = it * 256 + t;
        if (chunk < WMAT_HALVES / 8)
            *(half8*)&dst[chunk * 8] = *(const half8*)&tile[chunk * 8];
    }
}

// block (s,w) compacts indices of points in segment s needing window w. LDS atomics only.
__global__ __launch_bounds__(512) void bucket256_kernel(
    const float* __restrict__ x, const float* __restrict__ mids,
    int* __restrict__ cnt16, unsigned short* __restrict__ idx)
{
    const int s = blockIdx.x;              // 16 segments
    const int w = blockIdx.y;              // 16 windows
    __shared__ int lcnt;
    if (threadIdx.x == 0) lcnt = 0;
    __syncthreads();
    const float lo = mids[w] - DELTA;
    const float hi = mids[w + 1] + DELTA;
    const int lane = threadIdx.x & 63;
    unsigned short* dst = idx + (size_t)(w * NSEG + s) * CAPSEG;
#pragma unroll
    for (int it = 0; it < SEGPTS / 512; ++it) {
        int i = s * SEGPTS + it * 512 + threadIdx.x;
        float xv = x[i];
        bool need = (xv >= lo) && (xv <= hi);
        unsigned long long mask = __ballot(need);
        if (mask) {
            int leader = (int)__builtin_ctzll(mask);
            int total  = (int)__popcll(mask);
            int rank   = (int)__popcll(mask & ((1ull << lane) - 1ull));
            int base = 0;
            if (lane == leader) base = atomicAdd(&lcnt, total);   // LDS atomic
            base = __shfl(base, leader);
            int slot = base + rank;
            if (need && slot < CAPSEG) dst[slot] = (unsigned short)i;
        }
    }
    __syncthreads();
    if (threadIdx.x == 0) cnt16[w * NSEG + s] = lcnt;
}

// acc[c] = 16x16 tile c of Hlds[128rows x 128k] @ Wlds[128n x 128k]^T
__device__ __forceinline__ void gemm_tile(const _Float16* Hbase, const _Float16* Wbase,
                                          int row0, int m, int q, f32x4 acc[8]) {
    const f32x4 z = {0.f, 0.f, 0.f, 0.f};
#pragma unroll
    for (int c = 0; c < 8; ++c) acc[c] = z;
#pragma unroll
    for (int s = 0; s < 4; ++s) {
        half8 a = *(const half8*)(Hbase + (row0 + m) * HPAD + s * 32 + q * 8);
#pragma unroll
        for (int c = 0; c < 8; ++c) {
            half8 b = *(const half8*)(Wbase + (c * 16 + m) * HPAD + s * 32 + q * 8);
            acc[c] = __builtin_amdgcn_mfma_f32_16x16x32_f16(a, b, acc[c], 0, 0, 0);
        }
    }
}

__device__ __forceinline__ void act_store(_Float16* Hbase, const float* __restrict__ bias,
                                          int row0, int m, int q, const f32x4 acc[8]) {
#pragma unroll
    for (int c = 0; c < 8; ++c) {
        float b = bias[c * 16 + m];
#pragma unroll
        for (int r = 0; r < 4; ++r) {
            // C/D layout: col = lane&15 (=m), row = q*4 + r
            Hbase[(row0 + q * 4 + r) * HPAD + c * 16 + m] = (_Float16)tanh_fast(acc[c][r] + b);
        }
    }
}

__device__ __forceinline__ void stage_w(const float4* __restrict__ g, float4* l4, int t) {
    float4 r0 = g[t], r1 = g[t + 512], r2 = g[t + 1024], r3 = g[t + 1536];
    float4 r4;
    if (t < 128) r4 = g[t + 2048];
    l4[t] = r0; l4[t + 512] = r1; l4[t + 1024] = r2; l4[t + 1536] = r3;
    if (t < 128) l4[t + 2048] = r4;
}

__global__ __launch_bounds__(NTHR, 4) void fbpinn_main(
    const float* __restrict__ x,     const float* __restrict__ means,
    const float* __restrict__ stds,  const float* __restrict__ mids,
    const float* __restrict__ W_in,  const float* __restrict__ b_in,
    const float* __restrict__ b_hid, const float* __restrict__ W_out,
    const float* __restrict__ b_out, const _Float16* __restrict__ wt,
    const int* __restrict__ cnt16,   const unsigned short* __restrict__ idx,
    float* __restrict__ out)
{
    const int w    = blockIdx.y;
    const int base = blockIdx.x * TILE;

    __shared__ __align__(16) _Float16 Wlds[WMAT_HALVES];   // 34816 B
    __shared__ __align__(16) _Float16 Hlds[TILE * HPAD];   // 34816 B
    __shared__ float xs[TILE];
    __shared__ float wouts[NEUR];
    __shared__ unsigned short gis[TILE];
    __shared__ int csh[NSEG];

    const int t    = threadIdx.x;
    const int lane = t & 63;
    const int wave = t >> 6;
    const int m    = lane & 15;
    const int q    = lane >> 4;
    const int row0 = wave * 16;
    const int p    = t & 127;
    const int qq   = t >> 7;
    const int rsel = m & 3;

    if (t < NSEG) { int c = cnt16[w * NSEG + t]; csh[t] = c > CAPSEG ? CAPSEG : c; }
    __syncthreads();
    int total = 0;
#pragma unroll
    for (int k = 0; k < NSEG; ++k) total += csh[k];   // broadcast LDS reads
    if (base >= total) return;                        // uniform exit
    const int nvalid = min(TILE, total - base);

    // gather this chunk's points via segment resolution; clamp tail lanes.
    // R6 BUG fixed here: must test v against the TRUE running prefix (pre),
    // not segbase+csh[k] with a stale segbase.
    if (t < TILE) {
        int v = base + min(t, nvalid - 1);
        int seg = 0, segbase = 0, pre = 0;
#pragma unroll
        for (int k = 0; k < NSEG - 1; ++k) {
            pre += csh[k];                            // pre == pre[k+1]
            if (v >= pre) { seg = k + 1; segbase = pre; }
        }
        unsigned short gi = idx[(size_t)(w * NSEG + seg) * CAPSEG + (v - segbase)];
        gis[t] = gi;
        xs[t]  = x[gi];
    }
    stage_w((const float4*)(wt + (size_t)(0 * NW + w) * WMAT_HALVES), (float4*)Wlds, t);
    if (t < NEUR) wouts[t] = W_out[w * NEUR + t];
    __syncthreads();   // xs/gis/Wlds/wouts visible

    // layer 0 (1->128) fp32, b128 stores
    const float xn = (xs[p] - means[w]) * __builtin_amdgcn_rcpf(stds[w]);
    const float* win = W_in + w * NEUR;
    const float* bin = b_in + w * NEUR;
#pragma unroll
    for (int i8 = 0; i8 < 4; ++i8) {
        const int n0 = qq * 32 + i8 * 8;
        float4 wv0 = *(const float4*)&win[n0];
        float4 wv1 = *(const float4*)&win[n0 + 4];
        float4 bv0 = *(const float4*)&bin[n0];
        float4 bv1 = *(const float4*)&bin[n0 + 4];
        half8 hv;
        hv[0] = (_Float16)tanh_fast(fmaf(xn, wv0.x, bv0.x));
        hv[1] = (_Float16)tanh_fast(fmaf(xn, wv0.y, bv0.y));
        hv[2] = (_Float16)tanh_fast(fmaf(xn, wv0.z, bv0.z));
        hv[3] = (_Float16)tanh_fast(fmaf(xn, wv0.w, bv0.w));
        hv[4] = (_Float16)tanh_fast(fmaf(xn, wv1.x, bv1.x));
        hv[5] = (_Float16)tanh_fast(fmaf(xn, wv1.y, bv1.y));
        hv[6] = (_Float16)tanh_fast(fmaf(xn, wv1.z, bv1.z));
        hv[7] = (_Float16)tanh_fast(fmaf(xn, wv1.w, bv1.w));
        *(half8*)&Hlds[p * HPAD + n0] = hv;
    }
    __syncthreads();   // h1 visible

    f32x4 acc[8];
    gemm_tile(Hlds, Wlds, row0, m, q, acc);          // z2 = h1 @ W0^T-frag
    __syncthreads();

    stage_w((const float4*)(wt + (size_t)(1 * NW + w) * WMAT_HALVES), (float4*)Wlds, t);
    act_store(Hlds, b_hid + (0 * NW + w) * NEUR, row0, m, q, acc);   // h2
    __syncthreads();

    gemm_tile(Hlds, Wlds, row0, m, q, acc);          // z3 = h2 @ W1^T-frag

    // register epilogue: h3 = tanh(z3+b); out = h3 . W_out ; reduce over 16 m-lanes
    const float* bh1 = b_hid + (1 * NW + w) * NEUR;
    float t0 = 0.f, t1 = 0.f, t2 = 0.f, t3 = 0.f;
#pragma unroll
    for (int c = 0; c < 8; ++c) {
        float b  = bh1[c * 16 + m];
        float wo = wouts[c * 16 + m];
        t0 = fmaf(tanh_fast(acc[c][0] + b), wo, t0);
        t1 = fmaf(tanh_fast(acc[c][1] + b), wo, t1);
        t2 = fmaf(tanh_fast(acc[c][2] + b), wo, t2);
        t3 = fmaf(tanh_fast(acc[c][3] + b), wo, t3);
    }
    t0 += __shfl_xor(t0, 1); t1 += __shfl_xor(t1, 1);
    t2 += __shfl_xor(t2, 1); t3 += __shfl_xor(t3, 1);
    t0 += __shfl_xor(t0, 2); t1 += __shfl_xor(t1, 2);
    t2 += __shfl_xor(t2, 2); t3 += __shfl_xor(t3, 2);
    float v = (rsel == 0) ? t0 : (rsel == 1) ? t1 : (rsel == 2) ? t2 : t3;
    v += __shfl_xor(v, 4);
    v += __shfl_xor(v, 8);

    const int slot = row0 + q * 4 + rsel;
    if (m < 4 && slot < nvalid) {
        float u   = (v + b_out[w]) * U_SD + U_MEAN;
        float xv  = xs[slot];
        float xl  = (xv - mids[w])     * (1.0f / SIGMA);
        float xr  = (xv - mids[w + 1]) * (1.0f / SIGMA);
        float wf  = __builtin_amdgcn_rcpf(1.0f + __expf(xl)) *
                    __builtin_amdgcn_rcpf(1.0f + __expf(-xr));
        atomicAdd(&out[gis[slot]], wf * u);
    }
}

extern "C" void kernel_launch(void* const* d_in, const int* in_sizes, int n_in,
                              void* d_out, int out_size, void* d_ws, size_t ws_size,
                              hipStream_t stream) {
    const float* x     = (const float*)d_in[0];
    const float* means = (const float*)d_in[1];
    const float* stds  = (const float*)d_in[2];
    const float* mids  = (const float*)d_in[3];
    const float* W_in  = (const float*)d_in[4];
    const float* b_in  = (const float*)d_in[5];
    const float* W_hid = (const float*)d_in[6];
    const float* b_hid = (const float*)d_in[7];
    const float* W_out = (const float*)d_in[8];
    const float* b_out = (const float*)d_in[9];
    float* out = (float*)d_out;

    _Float16*       wt    = (_Float16*)d_ws;                          // 1,114,112 B
    int*            cnt16 = (int*)((char*)d_ws + CNT_OFF);            // 1 KB
    unsigned short* idx   = (unsigned short*)((char*)d_ws + IDX_OFF); // 1 MB  (total ~2.2 MB)

    hipMemsetAsync(out, 0, NPTS * sizeof(float), stream);
    prep2_kernel<<<2 * NW, 256, 0, stream>>>(W_hid, wt);
    bucket256_kernel<<<dim3(NSEG, NW), 512, 0, stream>>>(x, mids, cnt16, idx);
    fbpinn_main<<<dim3(CHUNKS, NW), NTHR, 0, stream>>>(
        x, means, stds, mids, W_in, b_in, b_hid, W_out, b_out, wt, cnt16, idx, out);
}

// Round 8
// 167.781 us; speedup vs baseline: 2.0976x; 1.0193x over previous
//
#include <hip/hip_runtime.h>

#define NW    16
#define NEUR  128
#define NPTS  65536
#define SIGMA 0.02f
#define U_MEAN 0.0f
#define U_SD   1.0f
#define DELTA 0.19f          // cull radius: err <= 2.1*11.4*exp(-(DELTA+0.0625)/SIGMA) ~ 8e-5

#define TILE   128          // points per block
#define NTHR   512          // 8 waves
#define HPAD   136          // 272B rows: 16B-aligned (132 caused misaligned-b128 HW replay, R2)
#define WMAT_HALVES (NEUR*HPAD)           // 17408 halves = 34816 B per matrix
#define WT_TOTAL (2*NW*WMAT_HALVES)       // 557056 halves = 1,114,112 B
#define WT_BYTES (WT_TOTAL*2)
#define CNT_OFF  WT_BYTES                 // 256 ints (cnt16[w*16+s])
#define IDX_OFF  (WT_BYTES + 1024)        // segmented u16 lists, 1 MB
#define NSEG   16
#define SEGPTS (NPTS/NSEG)                // 4096 points scanned per bucket block
#define CAPSEG 2048                       // max fill ~1910 (mean 1812 + 3sigma; edges ~1034)
#define CHUNKS 256                        // ceil(16*CAPSEG/TILE) upper bound

typedef _Float16 half8 __attribute__((ext_vector_type(8)));
typedef float    f32x4 __attribute__((ext_vector_type(4)));

__device__ __forceinline__ float tanh_fast(float x) {
    float e = __expf(2.0f * x);
    return 1.0f - 2.0f * __builtin_amdgcn_rcpf(1.0f + e);
}

// ONE aux dispatch (R7 forensics: ~14-15 us fixed cost PER DISPATCH in the
// harness graph timing — three small aux dispatches cost more in gaps than
// in kernel time). Roles by blockIdx.x:
//   [0,32)    prep: W_hid fp32 [lw][d][e] -> wt fp16 [lw][e][HPAD] via LDS transpose
//   [32,288)  bucket: segment s of window w -> compacted u16 list + cnt16
//   [288,320) zero out[]
__global__ __launch_bounds__(512) void aux_kernel(
    const float* __restrict__ W_hid, const float* __restrict__ x,
    const float* __restrict__ mids,  _Float16* __restrict__ wt,
    int* __restrict__ cnt16, unsigned short* __restrict__ idx,
    float* __restrict__ out)
{
    const int b = blockIdx.x;
    const int t = threadIdx.x;

    if (b < 32) {                          // ---- prep: one 128x128 matrix per block
        __shared__ __align__(16) _Float16 tile[NEUR * HPAD];   // 34816 B
        const int lw = b;
        const float4* src = (const float4*)(W_hid + (size_t)lw * NEUR * NEUR);
#pragma unroll
        for (int it = 0; it < 8; ++it) {   // 4096 float4, coalesced over e
            int f4 = it * 512 + t;
            int d  = f4 >> 5;
            int e0 = (f4 & 31) << 2;
            float4 v = src[f4];
            tile[(e0 + 0) * HPAD + d] = (_Float16)v.x;
            tile[(e0 + 1) * HPAD + d] = (_Float16)v.y;
            tile[(e0 + 2) * HPAD + d] = (_Float16)v.z;
            tile[(e0 + 3) * HPAD + d] = (_Float16)v.w;
        }
        if (t < NEUR) {                    // zero k-pad halves d in [128,136)
            half8 z; for (int j = 0; j < 8; ++j) z[j] = (_Float16)0.0f;
            *(half8*)&tile[t * HPAD + NEUR] = z;
        }
        __syncthreads();
        _Float16* dst = wt + (size_t)lw * WMAT_HALVES;
#pragma unroll
        for (int it = 0; it < 5; ++it) {   // 2176 half8 chunks, linear b128 copy
            int chunk = it * 512 + t;
            if (chunk < WMAT_HALVES / 8)
                *(half8*)&dst[chunk * 8] = *(const half8*)&tile[chunk * 8];
        }
    } else if (b < 288) {                  // ---- bucket: (segment, window)
        const int s = (b - 32) & (NSEG - 1);
        const int w = (b - 32) >> 4;
        __shared__ int lcnt;
        if (t == 0) lcnt = 0;
        __syncthreads();
        const float lo = mids[w] - DELTA;
        const float hi = mids[w + 1] + DELTA;
        const int lane = t & 63;
        unsigned short* dst = idx + (size_t)(w * NSEG + s) * CAPSEG;
#pragma unroll
        for (int it = 0; it < SEGPTS / 512; ++it) {
            int i = s * SEGPTS + it * 512 + t;
            float xv = x[i];
            bool need = (xv >= lo) && (xv <= hi);
            unsigned long long mask = __ballot(need);
            if (mask) {
                int leader = (int)__builtin_ctzll(mask);
                int total  = (int)__popcll(mask);
                int rank   = (int)__popcll(mask & ((1ull << lane) - 1ull));
                int base = 0;
                if (lane == leader) base = atomicAdd(&lcnt, total);   // LDS atomic
                base = __shfl(base, leader);
                int slot = base + rank;
                if (need && slot < CAPSEG) dst[slot] = (unsigned short)i;
            }
        }
        __syncthreads();
        if (t == 0) cnt16[w * NSEG + s] = lcnt;
    } else {                               // ---- zero out[]: 32 blocks x 512 x float4
        int i4 = (b - 288) * 512 + t;
        float4 z = {0.f, 0.f, 0.f, 0.f};
        ((float4*)out)[i4] = z;
    }
}

// acc[c] = 16x16 tile c of Hlds[128rows x 128k] @ Wlds[128n x 128k]^T
__device__ __forceinline__ void gemm_tile(const _Float16* Hbase, const _Float16* Wbase,
                                          int row0, int m, int q, f32x4 acc[8]) {
    const f32x4 z = {0.f, 0.f, 0.f, 0.f};
#pragma unroll
    for (int c = 0; c < 8; ++c) acc[c] = z;
#pragma unroll
    for (int s = 0; s < 4; ++s) {
        half8 a = *(const half8*)(Hbase + (row0 + m) * HPAD + s * 32 + q * 8);
#pragma unroll
        for (int c = 0; c < 8; ++c) {
            half8 b = *(const half8*)(Wbase + (c * 16 + m) * HPAD + s * 32 + q * 8);
            acc[c] = __builtin_amdgcn_mfma_f32_16x16x32_f16(a, b, acc[c], 0, 0, 0);
        }
    }
}

__device__ __forceinline__ void act_store(_Float16* Hbase, const float* __restrict__ bias,
                                          int row0, int m, int q, const f32x4 acc[8]) {
#pragma unroll
    for (int c = 0; c < 8; ++c) {
        float b = bias[c * 16 + m];
#pragma unroll
        for (int r = 0; r < 4; ++r) {
            // C/D layout: col = lane&15 (=m), row = q*4 + r
            Hbase[(row0 + q * 4 + r) * HPAD + c * 16 + m] = (_Float16)tanh_fast(acc[c][r] + b);
        }
    }
}

__device__ __forceinline__ void stage_w(const float4* __restrict__ g, float4* l4, int t) {
    float4 r0 = g[t], r1 = g[t + 512], r2 = g[t + 1024], r3 = g[t + 1536];
    float4 r4;
    if (t < 128) r4 = g[t + 2048];
    l4[t] = r0; l4[t + 512] = r1; l4[t + 1024] = r2; l4[t + 1536] = r3;
    if (t < 128) l4[t + 2048] = r4;
}

__global__ __launch_bounds__(NTHR, 4) void fbpinn_main(
    const float* __restrict__ x,     const float* __restrict__ means,
    const float* __restrict__ stds,  const float* __restrict__ mids,
    const float* __restrict__ W_in,  const float* __restrict__ b_in,
    const float* __restrict__ b_hid, const float* __restrict__ W_out,
    const float* __restrict__ b_out, const _Float16* __restrict__ wt,
    const int* __restrict__ cnt16,   const unsigned short* __restrict__ idx,
    float* __restrict__ out)
{
    const int w    = blockIdx.y;
    const int base = blockIdx.x * TILE;

    __shared__ __align__(16) _Float16 Wlds[WMAT_HALVES];   // 34816 B
    __shared__ __align__(16) _Float16 Hlds[TILE * HPAD];   // 34816 B
    __shared__ float xs[TILE];
    __shared__ float wouts[NEUR];
    __shared__ unsigned short gis[TILE];
    __shared__ int csh[NSEG];

    const int t    = threadIdx.x;
    const int lane = t & 63;
    const int wave = t >> 6;
    const int m    = lane & 15;
    const int q    = lane >> 4;
    const int row0 = wave * 16;
    const int p    = t & 127;
    const int qq   = t >> 7;
    const int rsel = m & 3;

    if (t < NSEG) { int c = cnt16[w * NSEG + t]; csh[t] = c > CAPSEG ? CAPSEG : c; }
    __syncthreads();
    int total = 0;
#pragma unroll
    for (int k = 0; k < NSEG; ++k) total += csh[k];   // broadcast LDS reads
    if (base >= total) return;                        // uniform exit
    const int nvalid = min(TILE, total - base);

    // gather via segment resolution against the TRUE running prefix (R6 bug fixed in R7)
    if (t < TILE) {
        int v = base + min(t, nvalid - 1);
        int seg = 0, segbase = 0, pre = 0;
#pragma unroll
        for (int k = 0; k < NSEG - 1; ++k) {
            pre += csh[k];                            // pre == pre[k+1]
            if (v >= pre) { seg = k + 1; segbase = pre; }
        }
        unsigned short gi = idx[(size_t)(w * NSEG + seg) * CAPSEG + (v - segbase)];
        gis[t] = gi;
        xs[t]  = x[gi];
    }
    stage_w((const float4*)(wt + (size_t)(0 * NW + w) * WMAT_HALVES), (float4*)Wlds, t);
    if (t < NEUR) wouts[t] = W_out[w * NEUR + t];
    __syncthreads();   // xs/gis/Wlds/wouts visible

    // layer 0 (1->128) fp32, b128 stores
    const float xn = (xs[p] - means[w]) * __builtin_amdgcn_rcpf(stds[w]);
    const float* win = W_in + w * NEUR;
    const float* bin = b_in + w * NEUR;
#pragma unroll
    for (int i8 = 0; i8 < 4; ++i8) {
        const int n0 = qq * 32 + i8 * 8;
        float4 wv0 = *(const float4*)&win[n0];
        float4 wv1 = *(const float4*)&win[n0 + 4];
        float4 bv0 = *(const float4*)&bin[n0];
        float4 bv1 = *(const float4*)&bin[n0 + 4];
        half8 hv;
        hv[0] = (_Float16)tanh_fast(fmaf(xn, wv0.x, bv0.x));
        hv[1] = (_Float16)tanh_fast(fmaf(xn, wv0.y, bv0.y));
        hv[2] = (_Float16)tanh_fast(fmaf(xn, wv0.z, bv0.z));
        hv[3] = (_Float16)tanh_fast(fmaf(xn, wv0.w, bv0.w));
        hv[4] = (_Float16)tanh_fast(fmaf(xn, wv1.x, bv1.x));
        hv[5] = (_Float16)tanh_fast(fmaf(xn, wv1.y, bv1.y));
        hv[6] = (_Float16)tanh_fast(fmaf(xn, wv1.z, bv1.z));
        hv[7] = (_Float16)tanh_fast(fmaf(xn, wv1.w, bv1.w));
        *(half8*)&Hlds[p * HPAD + n0] = hv;
    }
    __syncthreads();   // h1 visible

    f32x4 acc[8];
    gemm_tile(Hlds, Wlds, row0, m, q, acc);          // z2 = h1 @ W0^T-frag
    __syncthreads();

    stage_w((const float4*)(wt + (size_t)(1 * NW + w) * WMAT_HALVES), (float4*)Wlds, t);
    act_store(Hlds, b_hid + (0 * NW + w) * NEUR, row0, m, q, acc);   // h2
    __syncthreads();

    gemm_tile(Hlds, Wlds, row0, m, q, acc);          // z3 = h2 @ W1^T-frag

    // register epilogue: h3 = tanh(z3+b); out = h3 . W_out ; reduce over 16 m-lanes
    const float* bh1 = b_hid + (1 * NW + w) * NEUR;
    float t0 = 0.f, t1 = 0.f, t2 = 0.f, t3 = 0.f;
#pragma unroll
    for (int c = 0; c < 8; ++c) {
        float b  = bh1[c * 16 + m];
        float wo = wouts[c * 16 + m];
        t0 = fmaf(tanh_fast(acc[c][0] + b), wo, t0);
        t1 = fmaf(tanh_fast(acc[c][1] + b), wo, t1);
        t2 = fmaf(tanh_fast(acc[c][2] + b), wo, t2);
        t3 = fmaf(tanh_fast(acc[c][3] + b), wo, t3);
    }
    t0 += __shfl_xor(t0, 1); t1 += __shfl_xor(t1, 1);
    t2 += __shfl_xor(t2, 1); t3 += __shfl_xor(t3, 1);
    t0 += __shfl_xor(t0, 2); t1 += __shfl_xor(t1, 2);
    t2 += __shfl_xor(t2, 2); t3 += __shfl_xor(t3, 2);
    float v = (rsel == 0) ? t0 : (rsel == 1) ? t1 : (rsel == 2) ? t2 : t3;
    v += __shfl_xor(v, 4);
    v += __shfl_xor(v, 8);

    const int slot = row0 + q * 4 + rsel;
    if (m < 4 && slot < nvalid) {
        float u   = (v + b_out[w]) * U_SD + U_MEAN;
        float xv  = xs[slot];
        float xl  = (xv - mids[w])     * (1.0f / SIGMA);
        float xr  = (xv - mids[w + 1]) * (1.0f / SIGMA);
        float wf  = __builtin_amdgcn_rcpf(1.0f + __expf(xl)) *
                    __builtin_amdgcn_rcpf(1.0f + __expf(-xr));
        atomicAdd(&out[gis[slot]], wf * u);
    }
}

extern "C" void kernel_launch(void* const* d_in, const int* in_sizes, int n_in,
                              void* d_out, int out_size, void* d_ws, size_t ws_size,
                              hipStream_t stream) {
    const float* x     = (const float*)d_in[0];
    const float* means = (const float*)d_in[1];
    const float* stds  = (const float*)d_in[2];
    const float* mids  = (const float*)d_in[3];
    const float* W_in  = (const float*)d_in[4];
    const float* b_in  = (const float*)d_in[5];
    const float* W_hid = (const float*)d_in[6];
    const float* b_hid = (const float*)d_in[7];
    const float* W_out = (const float*)d_in[8];
    const float* b_out = (const float*)d_in[9];
    float* out = (float*)d_out;

    _Float16*       wt    = (_Float16*)d_ws;                          // 1,114,112 B
    int*            cnt16 = (int*)((char*)d_ws + CNT_OFF);            // 1 KB
    unsigned short* idx   = (unsigned short*)((char*)d_ws + IDX_OFF); // 1 MB  (total ~2.2 MB)

    aux_kernel<<<320, 512, 0, stream>>>(W_hid, x, mids, wt, cnt16, idx, out);
    fbpinn_main<<<dim3(CHUNKS, NW), NTHR, 0, stream>>>(
        x, means, stds, mids, W_in, b_in, b_hid, W_out, b_out, wt, cnt16, idx, out);
}

// Round 9
// 158.104 us; speedup vs baseline: 2.2260x; 1.0612x over previous
//
#include <hip/hip_runtime.h>

#define NW    16
#define NEUR  128
#define NPTS  65536
#define SIGMA 0.02f
#define U_MEAN 0.0f
#define U_SD   1.0f
#define DELTA 0.19f          // cull radius: err <= ~8e-5 (measured: absmax unchanged vs no-cull)

#define TILE   128          // points per block
#define NTHR   512          // 8 waves
#define HPAD   136          // 272B rows: 16B-aligned (132 caused misaligned-b128 HW replay, R2)
#define WMAT_HALVES (NEUR*HPAD)           // 17408 halves = 34816 B per matrix
#define WT_TOTAL (2*NW*WMAT_HALVES)       // 557056 halves = 1,114,112 B
#define WT_BYTES (WT_TOTAL*2)
#define CNT_OFF  WT_BYTES                 // 256 ints (cnt16[w*16+s])
#define IDX_OFF  (WT_BYTES + 1024)        // segmented u16 lists, 1 MB
#define NSEG   16
#define SEGPTS (NPTS/NSEG)                // 4096 points scanned per bucket block
#define CAPSEG 2048                       // max fill ~1910 (mean 1812 + 3sigma; edges ~1034)
#define CHUNKS 256                        // ceil(16*CAPSEG/TILE) upper bound

typedef _Float16 half8 __attribute__((ext_vector_type(8)));
typedef float    f32x4 __attribute__((ext_vector_type(4)));

__device__ __forceinline__ float tanh_fast(float x) {
    float e = __expf(2.0f * x);
    return 1.0f - 2.0f * __builtin_amdgcn_rcpf(1.0f + e);
}

// ONE aux dispatch. Roles by blockIdx.x:
//   [0,32)    prep: W_hid fp32 [lw][d][e] -> wt fp16 [lw][e][HPAD] via LDS transpose
//   [32,288)  bucket: segment s of window w -> compacted u16 list + cnt16
//   [288,320) zero out[]
__global__ __launch_bounds__(512) void aux_kernel(
    const float* __restrict__ W_hid, const float* __restrict__ x,
    const float* __restrict__ mids,  _Float16* __restrict__ wt,
    int* __restrict__ cnt16, unsigned short* __restrict__ idx,
    float* __restrict__ out)
{
    const int b = blockIdx.x;
    const int t = threadIdx.x;

    if (b < 32) {                          // ---- prep: one 128x128 matrix per block
        __shared__ __align__(16) _Float16 tile[NEUR * HPAD];   // 34816 B
        const int lw = b;
        const float4* src = (const float4*)(W_hid + (size_t)lw * NEUR * NEUR);
#pragma unroll
        for (int it = 0; it < 8; ++it) {   // 4096 float4, coalesced over e
            int f4 = it * 512 + t;
            int d  = f4 >> 5;
            int e0 = (f4 & 31) << 2;
            float4 v = src[f4];
            tile[(e0 + 0) * HPAD + d] = (_Float16)v.x;
            tile[(e0 + 1) * HPAD + d] = (_Float16)v.y;
            tile[(e0 + 2) * HPAD + d] = (_Float16)v.z;
            tile[(e0 + 3) * HPAD + d] = (_Float16)v.w;
        }
        if (t < NEUR) {                    // zero k-pad halves d in [128,136)
            half8 z; for (int j = 0; j < 8; ++j) z[j] = (_Float16)0.0f;
            *(half8*)&tile[t * HPAD + NEUR] = z;
        }
        __syncthreads();
        _Float16* dst = wt + (size_t)lw * WMAT_HALVES;
#pragma unroll
        for (int it = 0; it < 5; ++it) {   // 2176 half8 chunks, linear b128 copy
            int chunk = it * 512 + t;
            if (chunk < WMAT_HALVES / 8)
                *(half8*)&dst[chunk * 8] = *(const half8*)&tile[chunk * 8];
        }
    } else if (b < 288) {                  // ---- bucket: (segment, window)
        const int s = (b - 32) & (NSEG - 1);
        const int w = (b - 32) >> 4;
        __shared__ int lcnt;
        if (t == 0) lcnt = 0;
        __syncthreads();
        const float lo = mids[w] - DELTA;
        const float hi = mids[w + 1] + DELTA;
        const int lane = t & 63;
        unsigned short* dst = idx + (size_t)(w * NSEG + s) * CAPSEG;
#pragma unroll
        for (int it = 0; it < SEGPTS / 512; ++it) {
            int i = s * SEGPTS + it * 512 + t;
            float xv = x[i];
            bool need = (xv >= lo) && (xv <= hi);
            unsigned long long mask = __ballot(need);
            if (mask) {
                int leader = (int)__builtin_ctzll(mask);
                int total  = (int)__popcll(mask);
                int rank   = (int)__popcll(mask & ((1ull << lane) - 1ull));
                int base = 0;
                if (lane == leader) base = atomicAdd(&lcnt, total);   // LDS atomic
                base = __shfl(base, leader);
                int slot = base + rank;
                if (need && slot < CAPSEG) dst[slot] = (unsigned short)i;
            }
        }
        __syncthreads();
        if (t == 0) cnt16[w * NSEG + s] = lcnt;
    } else {                               // ---- zero out[]: 32 blocks x 512 x float4
        int i4 = (b - 288) * 512 + t;
        float4 z = {0.f, 0.f, 0.f, 0.f};
        ((float4*)out)[i4] = z;
    }
}

// acc[c] = 16x16 tile c of A[128rows x 128k] @ B[128n x 128k]^T  (A from LDS rows)
__device__ __forceinline__ void gemm_tile(const _Float16* Abase, const _Float16* Bbase,
                                          int row0, int m, int q, f32x4 acc[8]) {
#pragma unroll
    for (int s = 0; s < 4; ++s) {
        half8 a = *(const half8*)(Abase + (row0 + m) * HPAD + s * 32 + q * 8);
#pragma unroll
        for (int c = 0; c < 8; ++c) {
            half8 b = *(const half8*)(Bbase + (c * 16 + m) * HPAD + s * 32 + q * 8);
            acc[c] = __builtin_amdgcn_mfma_f32_16x16x32_f16(a, b, acc[c], 0, 0, 0);
        }
    }
}

__device__ __forceinline__ void act_store(_Float16* Hbase, const float* __restrict__ bias,
                                          int row0, int m, int q, const f32x4 acc[8]) {
#pragma unroll
    for (int c = 0; c < 8; ++c) {
        float b = bias[c * 16 + m];
#pragma unroll
        for (int r = 0; r < 4; ++r) {
            // C/D layout: col = lane&15 (=m), row = q*4 + r
            Hbase[(row0 + q * 4 + r) * HPAD + c * 16 + m] = (_Float16)tanh_fast(acc[c][r] + b);
        }
    }
}

__device__ __forceinline__ void stage_w(const float4* __restrict__ g, float4* l4, int t) {
    float4 r0 = g[t], r1 = g[t + 512], r2 = g[t + 1024], r3 = g[t + 1536];
    float4 r4;
    if (t < 128) r4 = g[t + 2048];
    l4[t] = r0; l4[t + 512] = r1; l4[t + 1024] = r2; l4[t + 1536] = r3;
    if (t < 128) l4[t + 2048] = r4;
}

__global__ __launch_bounds__(NTHR, 4) void fbpinn_main(
    const float* __restrict__ x,     const float* __restrict__ means,
    const float* __restrict__ stds,  const float* __restrict__ mids,
    const float* __restrict__ W_in,  const float* __restrict__ b_in,
    const float* __restrict__ b_hid, const float* __restrict__ W_out,
    const float* __restrict__ b_out, const _Float16* __restrict__ wt,
    const int* __restrict__ cnt16,   const unsigned short* __restrict__ idx,
    float* __restrict__ out)
{
    const int w    = blockIdx.y;
    const int base = blockIdx.x * TILE;

    // WA: W0 during GEMM1, then reused for h2 (GEMM2's A). WB: W1 for GEMM2's B.
    __shared__ __align__(16) _Float16 WA[WMAT_HALVES];   // 34816 B
    __shared__ __align__(16) _Float16 WB[WMAT_HALVES];   // 34816 B
    __shared__ float xs[TILE];
    __shared__ float wouts[NEUR];
    __shared__ unsigned short gis[TILE];

    const int t    = threadIdx.x;
    const int lane = t & 63;
    const int wave = t >> 6;
    const int m    = lane & 15;
    const int q    = lane >> 4;
    const int row0 = wave * 16;
    const int rsel = m & 3;

    // uniform per-thread scan of cnt16 (w uniform, k unrolled -> scalar loads; no LDS, no barrier)
    int csh[NSEG];
    int total = 0;
#pragma unroll
    for (int k = 0; k < NSEG; ++k) {
        int c = cnt16[w * NSEG + k];
        c = c > CAPSEG ? CAPSEG : c;
        csh[k] = c;
        total += c;
    }
    if (base >= total) return;                        // uniform exit
    const int nvalid = min(TILE, total - base);

    // gather via segment resolution against the true running prefix (R7 fix)
    if (t < TILE) {
        int v = base + min(t, nvalid - 1);
        int seg = 0, segbase = 0, pre = 0;
#pragma unroll
        for (int k = 0; k < NSEG - 1; ++k) {
            pre += csh[k];                            // pre == pre[k+1]
            if (v >= pre) { seg = k + 1; segbase = pre; }
        }
        unsigned short gi = idx[(size_t)(w * NSEG + seg) * CAPSEG + (v - segbase)];
        gis[t] = gi;
        xs[t]  = x[gi];
    }
    stage_w((const float4*)(wt + (size_t)(0 * NW + w) * WMAT_HALVES), (float4*)WA, t);
    stage_w((const float4*)(wt + (size_t)(1 * NW + w) * WMAT_HALVES), (float4*)WB, t);
    if (t < NEUR) wouts[t] = W_out[w * NEUR + t];
    __syncthreads();   // barrier 1: xs/gis/WA/WB/wouts visible

    // layer 0 straight into GEMM1 A-fragments (registers; no LDS round-trip).
    // Thread (m,q) owns point row0+m, neurons n = s*32+q*8+j — exactly its A-frag.
    const float xn = (xs[row0 + m] - means[w]) * __builtin_amdgcn_rcpf(stds[w]);
    const float* win = W_in + w * NEUR;
    const float* bin = b_in + w * NEUR;
    half8 af[4];
#pragma unroll
    for (int s = 0; s < 4; ++s) {
        const int n0 = s * 32 + q * 8;
        float4 wv0 = *(const float4*)&win[n0];
        float4 wv1 = *(const float4*)&win[n0 + 4];
        float4 bv0 = *(const float4*)&bin[n0];
        float4 bv1 = *(const float4*)&bin[n0 + 4];
        af[s][0] = (_Float16)tanh_fast(fmaf(xn, wv0.x, bv0.x));
        af[s][1] = (_Float16)tanh_fast(fmaf(xn, wv0.y, bv0.y));
        af[s][2] = (_Float16)tanh_fast(fmaf(xn, wv0.z, bv0.z));
        af[s][3] = (_Float16)tanh_fast(fmaf(xn, wv0.w, bv0.w));
        af[s][4] = (_Float16)tanh_fast(fmaf(xn, wv1.x, bv1.x));
        af[s][5] = (_Float16)tanh_fast(fmaf(xn, wv1.y, bv1.y));
        af[s][6] = (_Float16)tanh_fast(fmaf(xn, wv1.z, bv1.z));
        af[s][7] = (_Float16)tanh_fast(fmaf(xn, wv1.w, bv1.w));
    }

    // GEMM1: z2 = h1 @ W0^T-frag (A from registers, B from WA)
    f32x4 acc[8];
    const f32x4 zz = {0.f, 0.f, 0.f, 0.f};
#pragma unroll
    for (int c = 0; c < 8; ++c) acc[c] = zz;
#pragma unroll
    for (int s = 0; s < 4; ++s) {
#pragma unroll
        for (int c = 0; c < 8; ++c) {
            half8 b = *(const half8*)(WA + (c * 16 + m) * HPAD + s * 32 + q * 8);
            acc[c] = __builtin_amdgcn_mfma_f32_16x16x32_f16(af[s], b, acc[c], 0, 0, 0);
        }
    }
    __syncthreads();   // barrier 2: GEMM1 done reading WA

    act_store(WA, b_hid + (0 * NW + w) * NEUR, row0, m, q, acc);   // h2 -> WA
    __syncthreads();   // barrier 3: h2 visible

    // GEMM2: z3 = h2 @ W1^T-frag (A rows from WA, B from WB)
#pragma unroll
    for (int c = 0; c < 8; ++c) acc[c] = zz;
    gemm_tile(WA, WB, row0, m, q, acc);

    // register epilogue: h3 = tanh(z3+b); out = h3 . W_out ; reduce over 16 m-lanes
    const float* bh1 = b_hid + (1 * NW + w) * NEUR;
    float t0 = 0.f, t1 = 0.f, t2 = 0.f, t3 = 0.f;
#pragma unroll
    for (int c = 0; c < 8; ++c) {
        float b  = bh1[c * 16 + m];
        float wo = wouts[c * 16 + m];
        t0 = fmaf(tanh_fast(acc[c][0] + b), wo, t0);
        t1 = fmaf(tanh_fast(acc[c][1] + b), wo, t1);
        t2 = fmaf(tanh_fast(acc[c][2] + b), wo, t2);
        t3 = fmaf(tanh_fast(acc[c][3] + b), wo, t3);
    }
    t0 += __shfl_xor(t0, 1); t1 += __shfl_xor(t1, 1);
    t2 += __shfl_xor(t2, 1); t3 += __shfl_xor(t3, 1);
    t0 += __shfl_xor(t0, 2); t1 += __shfl_xor(t1, 2);
    t2 += __shfl_xor(t2, 2); t3 += __shfl_xor(t3, 2);
    float v = (rsel == 0) ? t0 : (rsel == 1) ? t1 : (rsel == 2) ? t2 : t3;
    v += __shfl_xor(v, 4);
    v += __shfl_xor(v, 8);

    const int slot = row0 + q * 4 + rsel;
    if (m < 4 && slot < nvalid) {
        float u   = (v + b_out[w]) * U_SD + U_MEAN;
        float xv  = xs[slot];
        float xl  = (xv - mids[w])     * (1.0f / SIGMA);
        float xr  = (xv - mids[w + 1]) * (1.0f / SIGMA);
        float wf  = __builtin_amdgcn_rcpf(1.0f + __expf(xl)) *
                    __builtin_amdgcn_rcpf(1.0f + __expf(-xr));
        atomicAdd(&out[gis[slot]], wf * u);
    }
}

extern "C" void kernel_launch(void* const* d_in, const int* in_sizes, int n_in,
                              void* d_out, int out_size, void* d_ws, size_t ws_size,
                              hipStream_t stream) {
    const float* x     = (const float*)d_in[0];
    const float* means = (const float*)d_in[1];
    const float* stds  = (const float*)d_in[2];
    const float* mids  = (const float*)d_in[3];
    const float* W_in  = (const float*)d_in[4];
    const float* b_in  = (const float*)d_in[5];
    const float* W_hid = (const float*)d_in[6];
    const float* b_hid = (const float*)d_in[7];
    const float* W_out = (const float*)d_in[8];
    const float* b_out = (const float*)d_in[9];
    float* out = (float*)d_out;

    _Float16*       wt    = (_Float16*)d_ws;                          // 1,114,112 B
    int*            cnt16 = (int*)((char*)d_ws + CNT_OFF);            // 1 KB
    unsigned short* idx   = (unsigned short*)((char*)d_ws + IDX_OFF); // 1 MB  (total ~2.2 MB)

    aux_kernel<<<320, 512, 0, stream>>>(W_hid, x, mids, wt, cnt16, idx, out);
    fbpinn_main<<<dim3(CHUNKS, NW), NTHR, 0, stream>>>(
        x, means, stds, mids, W_in, b_in, b_hid, W_out, b_out, wt, cnt16, idx, out);
}